// Round 1
// baseline (799.312 us; speedup 1.0000x reference)
//
#include <hip/hip_runtime.h>
#include <hip/hip_bf16.h>

#define S_LEN 2048
#define BATCH 2
#define DMODEL 256
#define NHEAD 8
#define DKH 32
#define NTOK (S_LEN * BATCH)
#define OUT0_ELEMS ((size_t)NTOK * DMODEL)
#define SW (S_LEN / 32)  // mask words per row

typedef __bf16 bf16_t;
typedef __bf16 bf16x8 __attribute__((ext_vector_type(8)));
typedef __bf16 bf16x4 __attribute__((ext_vector_type(4)));
typedef float f32x4 __attribute__((ext_vector_type(4)));

#define MFMA16(a, b, c) __builtin_amdgcn_mfma_f32_16x16x32_bf16(a, b, c, 0, 0, 0)

// -------- kernel 0: dtype probe. flag=1 if inputs are fp32, 0 if bf16 -------
__global__ void k_probe(const unsigned short* __restrict__ q, int* __restrict__ flag) {
  if (threadIdx.x == 0 && blockIdx.x == 0) {
    int good = 0;
    for (int i = 0; i < 512; i += 2) {
      unsigned short u = q[i];
      int e = (u >> 7) & 0xFF;
      if ((u & 0x7FFF) == 0 || (e >= 110 && e <= 135)) good++;
    }
    *flag = (good >= 200) ? 0 : 1;
  }
}

// -------- kernel 0b: canonicalize q,k,v to bf16 (fused 3-tensor) ------------
__global__ __launch_bounds__(256) void k_convert3(
    const void* __restrict__ s0, const void* __restrict__ s1,
    const void* __restrict__ s2, bf16_t* __restrict__ d0,
    bf16_t* __restrict__ d1, bf16_t* __restrict__ d2, int n,
    const int* __restrict__ flag) {
  const void* src = (blockIdx.y == 0) ? s0 : (blockIdx.y == 1) ? s1 : s2;
  bf16_t* dst = (blockIdx.y == 0) ? d0 : (blockIdx.y == 1) ? d1 : d2;
  int i = blockIdx.x * 256 + threadIdx.x;
  if (i >= n) return;
  if (*flag) dst[i] = (bf16_t)((const float*)src)[i];
  else       dst[i] = ((const bf16_t*)src)[i];
}

// ---------------- kernel 1: transpose the 4 weight matrices -----------------
__global__ __launch_bounds__(256) void k_transpose_w(
    const void* __restrict__ w_q, const void* __restrict__ w_k,
    const void* __restrict__ w_v, const void* __restrict__ w_fc,
    bf16_t* __restrict__ wt, const int* __restrict__ flag) {
  __shared__ bf16_t tile[32][33];
  const void* w = (blockIdx.z == 0) ? w_q : (blockIdx.z == 1) ? w_k
                                       : (blockIdx.z == 2) ? w_v : w_fc;
  int f = *flag;
  bf16_t* o = wt + (size_t)blockIdx.z * DMODEL * DMODEL;
  int tx = threadIdx.x, ty = threadIdx.y;
  int x = blockIdx.x * 32 + tx;
  int y0 = blockIdx.y * 32;
  for (int j = ty; j < 32; j += 8) {
    size_t idx = (size_t)(y0 + j) * DMODEL + x;
    float v = f ? ((const float*)w)[idx] : (float)((const bf16_t*)w)[idx];
    tile[j][tx] = (bf16_t)v;
  }
  __syncthreads();
  for (int j = ty; j < 32; j += 8)
    o[(size_t)(blockIdx.x * 32 + j) * DMODEL + y0 + tx] = tile[tx][j];
}

// ---------------- kernel 2: QKV projections via MFMA ------------------------
__global__ __launch_bounds__(256) void k_proj(
    const bf16_t* __restrict__ qin, const bf16_t* __restrict__ kin,
    const bf16_t* __restrict__ vin, const bf16_t* __restrict__ wt,
    bf16_t* __restrict__ qhi, bf16_t* __restrict__ qlo,
    bf16_t* __restrict__ khi, bf16_t* __restrict__ klo,
    bf16_t* __restrict__ vt) {
  int mat = blockIdx.z;
  const bf16_t* x = (mat == 0) ? qin : (mat == 1) ? kin : vin;
  const bf16_t* wm = wt + (size_t)mat * DMODEL * DMODEL;
  int t0 = blockIdx.x * 16;
  int lane = threadIdx.x & 63, wave = threadIdx.x >> 6;
  int col = lane & 15, quad = lane >> 4;
  f32x4 acc[4] = {};
  const bf16_t* xrow = x + (size_t)(t0 + col) * DMODEL + quad * 8;
  for (int kk = 0; kk < 8; kk++) {
    bf16x8 a = *(const bf16x8*)(xrow + kk * 32);
#pragma unroll
    for (int nt = 0; nt < 4; nt++) {
      int n0 = wave * 64 + nt * 16;
      bf16x8 bw = *(const bf16x8*)(wm + (size_t)(n0 + col) * DMODEL + kk * 32 + quad * 8);
      acc[nt] = MFMA16(a, bw, acc[nt]);
    }
  }
  const float qscale = 0.17677669529663687f;  // 1/sqrt(32)
#pragma unroll
  for (int nt = 0; nt < 4; nt++) {
    int n = wave * 64 + nt * 16 + col;
    int h = n >> 5, dk = n & 31;
#pragma unroll
    for (int r = 0; r < 4; r++) {
      int t = t0 + quad * 4 + r;
      int s = t >> 1, bb = t & 1;
      float val = acc[nt][r];
      if (mat == 0) val *= qscale;
      if (mat <= 1) {
        bf16_t hi = (bf16_t)val;
        bf16_t lo = (bf16_t)(val - (float)hi);
        size_t idx = ((size_t)(bb * NHEAD + h) * S_LEN + s) * DKH + dk;
        if (mat == 0) { qhi[idx] = hi; qlo[idx] = lo; }
        else         { khi[idx] = hi; klo[idx] = lo; }
      } else {
        vt[((size_t)(bb * NHEAD + h) * DKH + dk) * S_LEN + s] = (bf16_t)val;
      }
    }
  }
}

// ---------------- kernel 2b: transpose graph_pos + pack mask ----------------
// gp [k=2048][q=2048][h=8] -> bias in [h][q][k] layout.
// MODE 0: single bf16 copy into gpt (workspace).
// MODE 1: flag-dtype copies duplicated into the attno region of d_out for
//         b=0 and b=1 (read-then-overwritten in place by k_attn).
// Also bit-packs mask: 64 uint32 words per block.
template <int MODE>
__global__ __launch_bounds__(256) void k_tr_gp(
    const void* __restrict__ gp, bf16_t* __restrict__ gpt,
    void* __restrict__ attno_raw, const int* __restrict__ mask,
    unsigned int* __restrict__ mbits, const int* __restrict__ flag) {
  __shared__ float tile[32][8][32];  // [k][h][q], 32 KB
  int is32 = *flag;
  int tid = threadIdx.x;
  int k0 = blockIdx.x * 32, q0 = blockIdx.y * 32;
  int ci = tid & 63, krl = tid >> 6;
#pragma unroll
  for (int p = 0; p < 8; p++) {
    int kr = p * 4 + krl;
    size_t base = ((size_t)(k0 + kr) * S_LEN + q0) * NHEAD + ci * 4;
    f32x4 v;
    if (is32) {
      v = __builtin_nontemporal_load((const f32x4*)((const float*)gp + base));
    } else {
      bf16x4 bv = *(const bf16x4*)((const bf16_t*)gp + base);
      v[0] = (float)bv[0]; v[1] = (float)bv[1];
      v[2] = (float)bv[2]; v[3] = (float)bv[3];
    }
    int qq = ci >> 1, hb = (ci & 1) * 4;  // 4 consecutive elems = 4 h of one q
    tile[kr][hb + 0][qq] = v[0];
    tile[kr][hb + 1][qq] = v[1];
    tile[kr][hb + 2][qq] = v[2];
    tile[kr][hb + 3][qq] = v[3];
  }
  __syncthreads();
  int h = tid >> 5, q = tid & 31;
  if (MODE == 0) {
    bf16_t* orow = gpt + ((size_t)h * S_LEN + q0 + q) * S_LEN + k0;
#pragma unroll
    for (int j = 0; j < 4; j++) {
      bf16x8 o;
#pragma unroll
      for (int i2 = 0; i2 < 8; i2++) o[i2] = (bf16_t)tile[j * 8 + i2][h][q];
      *(bf16x8*)(orow + j * 8) = o;
    }
  } else {
    size_t ro = ((size_t)h * S_LEN + q0 + q) * S_LEN + k0;
    size_t bs = (size_t)NHEAD * S_LEN * S_LEN;
    if (is32) {
      float* o0 = (float*)attno_raw + OUT0_ELEMS + ro;
#pragma unroll
      for (int j = 0; j < 8; j++) {
        f32x4 o;
#pragma unroll
        for (int i2 = 0; i2 < 4; i2++) o[i2] = tile[j * 4 + i2][h][q];
        *(f32x4*)(o0 + j * 4) = o;
        *(f32x4*)(o0 + bs + j * 4) = o;
      }
    } else {
      bf16_t* o0 = (bf16_t*)attno_raw + OUT0_ELEMS + ro;
#pragma unroll
      for (int j = 0; j < 4; j++) {
        bf16x8 o;
#pragma unroll
        for (int i2 = 0; i2 < 8; i2++) o[i2] = (bf16_t)tile[j * 8 + i2][h][q];
        *(bf16x8*)(o0 + j * 8) = o;
        *(bf16x8*)(o0 + bs + j * 8) = o;
      }
    }
  }
  // ---- mask bit-pack: this block handles 64 words (64*32 mask ints) ----
  if (tid < 64) {
    int w = (blockIdx.y * 64 + blockIdx.x) * 64 + tid;  // 0..262143
    const int* src = mask + (size_t)w * 32;
    unsigned int bits = 0;
#pragma unroll
    for (int j = 0; j < 32; j += 4) {
      int4 m = *(const int4*)(src + j);
      if (m.x) bits |= 1u << j;
      if (m.y) bits |= 1u << (j + 1);
      if (m.z) bits |= 1u << (j + 2);
      if (m.w) bits |= 1u << (j + 3);
    }
    mbits[w] = bits;
  }
}

// ---------------- kernel 3: attention ---------------------------------------
// BMODE 0: bias read as bf16 from gpt[h][q][k] (workspace).
// BMODE 1: bias read (flag dtype) from the attno region of d_out itself,
//          then overwritten with attno by the same wave (data-dep ordered).
template <int BMODE>
__global__ __launch_bounds__(256) void k_attn(
    const bf16_t* __restrict__ qhi, const bf16_t* __restrict__ qlo,
    const bf16_t* __restrict__ khi, const bf16_t* __restrict__ klo,
    const bf16_t* __restrict__ vtg, const bf16_t* __restrict__ gpt,
    const unsigned int* __restrict__ mbits, void* __restrict__ attno_raw,
    float* __restrict__ attn_out, const int* __restrict__ flag) {
  __shared__ __align__(16) bf16_t lds_p[4][16][72];
  __shared__ __align__(16) bf16_t lds_pb[4][16][72];
  __shared__ float lds_m[4][16];
  __shared__ float lds_l[4][16];
  __shared__ float lds_o[4][16][34];

  int is32 = *flag;
  float*  attno_f = (float*)attno_raw + OUT0_ELEMS;
  bf16_t* attno_b = (bf16_t*)attno_raw + OUT0_ELEMS;

  int h = blockIdx.y, b = blockIdx.z;
  int lane = threadIdx.x & 63, wave = threadIdx.x >> 6;
  int col = lane & 15, quad = lane >> 4;
  int q0 = blockIdx.x * 16;
  int kbase = wave * 512;
  size_t head = (size_t)(b * NHEAD + h);
  const bf16_t* Qh = qhi + head * S_LEN * DKH;
  const bf16_t* Ql = qlo + head * S_LEN * DKH;
  const bf16_t* Kh = khi + head * S_LEN * DKH;
  const bf16_t* Kl = klo + head * S_LEN * DKH;
  const bf16_t* Vt = vtg + head * DKH * S_LEN;
  const unsigned int* mrow =
      mbits + ((size_t)b * S_LEN + q0 + col) * SW + (kbase >> 5);
  const bf16_t* gprow = gpt + ((size_t)h * S_LEN + q0 + col) * S_LEN + kbase;
  size_t brow = head * S_LEN * S_LEN + (size_t)(q0 + col) * S_LEN + kbase;

  bf16x8 qhF = *(const bf16x8*)(Qh + (q0 + col) * DKH + quad * 8);
  bf16x8 qlF = *(const bf16x8*)(Ql + (q0 + col) * DKH + quad * 8);

  // ---- pass 1: per-wave online softmax stats over this wave's 512 keys ----
  float m = -3.0e38f, l = 0.f;
  for (int t = 0; t < 32; t++) {
    int k0 = kbase + t * 16;
    bf16x8 khF = *(const bf16x8*)(Kh + (size_t)(k0 + col) * DKH + quad * 8);
    bf16x8 klF = *(const bf16x8*)(Kl + (size_t)(k0 + col) * DKH + quad * 8);
    f32x4 sc = {};
    sc = MFMA16(khF, qhF, sc);
    sc = MFMA16(khF, qlF, sc);
    sc = MFMA16(klF, qhF, sc);
    unsigned int mw = mrow[t >> 1];
    int mb = (int)(mw >> ((t & 1) * 16 + quad * 4)) & 0xF;
    float s0 = (mb & 1) ? sc[0] : -1e9f;
    float s1 = (mb & 2) ? sc[1] : -1e9f;
    float s2 = (mb & 4) ? sc[2] : -1e9f;
    float s3 = (mb & 8) ? sc[3] : -1e9f;
    float tm = fmaxf(fmaxf(s0, s1), fmaxf(s2, s3));
    float m2 = fmaxf(m, tm);
    l = l * __expf(m - m2) + __expf(s0 - m2) + __expf(s1 - m2) +
        __expf(s2 - m2) + __expf(s3 - m2);
    m = m2;
  }
#pragma unroll
  for (int off = 16; off < 64; off <<= 1) {
    float mo = __shfl_xor(m, off);
    float lo2 = __shfl_xor(l, off);
    float mn = fmaxf(m, mo);
    l = l * __expf(m - mn) + lo2 * __expf(mo - mn);
    m = mn;
  }
  if (lane < 16) { lds_m[wave][lane] = m; lds_l[wave][lane] = l; }
  __syncthreads();
  {
    float mg = -3.0e38f;
#pragma unroll
    for (int w = 0; w < 4; w++) mg = fmaxf(mg, lds_m[w][col]);
    float lg = 0.f;
#pragma unroll
    for (int w = 0; w < 4; w++) lg += lds_l[w][col] * __expf(lds_m[w][col] - mg);
    m = mg;
    l = lg;
  }
  float invl = 1.0f / l;

  // ---- pass 2: recompute, emit attno, accumulate PV ----
  // no __syncthreads in this loop: lds_p/lds_pb are per-wave private.
  f32x4 oacc[2] = {};
  for (int c = 0; c < 8; c++) {
#pragma unroll
    for (int tt = 0; tt < 4; tt++) {
      int k0 = kbase + c * 64 + tt * 16;
      bf16x8 khF = *(const bf16x8*)(Kh + (size_t)(k0 + col) * DKH + quad * 8);
      bf16x8 klF = *(const bf16x8*)(Kl + (size_t)(k0 + col) * DKH + quad * 8);
      f32x4 sc = {};
      sc = MFMA16(khF, qhF, sc);
      sc = MFMA16(khF, qlF, sc);
      sc = MFMA16(klF, qhF, sc);
      unsigned int mw = mrow[c * 2 + (tt >> 1)];
      int mb = (int)(mw >> ((tt & 1) * 16 + quad * 4)) & 0xF;
      float bias[4];
      if (BMODE == 0) {
        bf16x4 b4 = *(const bf16x4*)(gprow + c * 64 + tt * 16 + quad * 4);
#pragma unroll
        for (int r = 0; r < 4; r++) bias[r] = (float)b4[r];
      } else {
        if (is32) {
          f32x4 b4 = *(const f32x4*)(attno_f + brow + c * 64 + tt * 16 + quad * 4);
#pragma unroll
          for (int r = 0; r < 4; r++) bias[r] = b4[r];
        } else {
          bf16x4 b4 = *(const bf16x4*)(attno_b + brow + c * 64 + tt * 16 + quad * 4);
#pragma unroll
          for (int r = 0; r < 4; r++) bias[r] = (float)b4[r];
        }
      }
      bf16x4 pv, pbv;
#pragma unroll
      for (int r = 0; r < 4; r++) {
        float sv = (mb & (1 << r)) ? sc[r] : -1e9f;
        float p = __expf(sv - m) * invl;
        pv[r] = (bf16_t)p;
        pbv[r] = (bf16_t)(p * bias[r]);
      }
      *(bf16x4*)&lds_p[wave][col][tt * 16 + quad * 4] = pv;
      *(bf16x4*)&lds_pb[wave][col][tt * 16 + quad * 4] = pbv;
    }
    {  // attno write: 16 rows x 64 keys per wave-chunk (nontemporal)
      int r = lane >> 2, part = lane & 3;
      size_t base = head * S_LEN * S_LEN + (size_t)(q0 + r) * S_LEN + kbase + c * 64 + part * 16;
      if (is32) {
#pragma unroll
        for (int jj = 0; jj < 4; jj++) {
          f32x4 vv;
#pragma unroll
          for (int ii = 0; ii < 4; ii++)
            vv[ii] = (float)lds_p[wave][r][part * 16 + jj * 4 + ii];
          __builtin_nontemporal_store(vv, (f32x4*)(attno_f + base + jj * 4));
        }
      } else {
        bf16x8 v0 = *(const bf16x8*)&lds_p[wave][r][part * 16];
        bf16x8 v1 = *(const bf16x8*)&lds_p[wave][r][part * 16 + 8];
        __builtin_nontemporal_store(v0, (bf16x8*)(attno_b + base));
        __builtin_nontemporal_store(v1, (bf16x8*)(attno_b + base + 8));
      }
    }
#pragma unroll
    for (int ks = 0; ks < 2; ks++) {
      bf16x8 pf = *(const bf16x8*)&lds_pb[wave][col][ks * 32 + quad * 8];
#pragma unroll
      for (int dt = 0; dt < 2; dt++) {
        bf16x8 vf = *(const bf16x8*)(Vt + (size_t)(dt * 16 + col) * S_LEN + kbase + c * 64 + ks * 32 + quad * 8);
        oacc[dt] = MFMA16(vf, pf, oacc[dt]);
      }
    }
  }
  // combine O across waves; wave 0 stores fp32 to ws
#pragma unroll
  for (int dt = 0; dt < 2; dt++)
#pragma unroll
    for (int r = 0; r < 4; r++)
      lds_o[wave][col][dt * 16 + quad * 4 + r] = oacc[dt][r];
  __syncthreads();
  if (wave == 0) {
    int t = (q0 + col) * BATCH + b;
#pragma unroll
    for (int dt = 0; dt < 2; dt++) {
      float4 vv;
      vv.x = lds_o[0][col][dt * 16 + quad * 4 + 0] + lds_o[1][col][dt * 16 + quad * 4 + 0] +
             lds_o[2][col][dt * 16 + quad * 4 + 0] + lds_o[3][col][dt * 16 + quad * 4 + 0];
      vv.y = lds_o[0][col][dt * 16 + quad * 4 + 1] + lds_o[1][col][dt * 16 + quad * 4 + 1] +
             lds_o[2][col][dt * 16 + quad * 4 + 1] + lds_o[3][col][dt * 16 + quad * 4 + 1];
      vv.z = lds_o[0][col][dt * 16 + quad * 4 + 2] + lds_o[1][col][dt * 16 + quad * 4 + 2] +
             lds_o[2][col][dt * 16 + quad * 4 + 2] + lds_o[3][col][dt * 16 + quad * 4 + 2];
      vv.w = lds_o[0][col][dt * 16 + quad * 4 + 3] + lds_o[1][col][dt * 16 + quad * 4 + 3] +
             lds_o[2][col][dt * 16 + quad * 4 + 3] + lds_o[3][col][dt * 16 + quad * 4 + 3];
      *(float4*)(attn_out + (size_t)t * DMODEL + h * DKH + dt * 16 + quad * 4) = vv;
    }
  }
}

// ---------------- kernel 4: FC + residual + LayerNorm -----------------------
__global__ __launch_bounds__(256) void k_fc_ln(
    const float* __restrict__ attn_out, const bf16_t* __restrict__ wtfc,
    const bf16_t* __restrict__ qc, const void* __restrict__ gamma,
    const void* __restrict__ beta, void* __restrict__ out0,
    const int* __restrict__ flag) {
  __shared__ float lds_sx[4][16];
  __shared__ float lds_sq[4][16];
  int is32 = *flag;
  int t0 = blockIdx.x * 16;
  int lane = threadIdx.x & 63, wave = threadIdx.x >> 6;
  int col = lane & 15, quad = lane >> 4;
  f32x4 acc[4] = {};
  const float* arow = attn_out + (size_t)(t0 + col) * DMODEL + quad * 8;
  for (int kk = 0; kk < 8; kk++) {
    float4 a0 = *(const float4*)(arow + kk * 32);
    float4 a1 = *(const float4*)(arow + kk * 32 + 4);
    float av[8] = {a0.x, a0.y, a0.z, a0.w, a1.x, a1.y, a1.z, a1.w};
    bf16x8 ahi, alo;
#pragma unroll
    for (int j = 0; j < 8; j++) {
      bf16_t hi = (bf16_t)av[j];
      ahi[j] = hi;
      alo[j] = (bf16_t)(av[j] - (float)hi);
    }
#pragma unroll
    for (int nt = 0; nt < 4; nt++) {
      int n0 = wave * 64 + nt * 16;
      bf16x8 bfr = *(const bf16x8*)(wtfc + (size_t)(n0 + col) * DMODEL + kk * 32 + quad * 8);
      acc[nt] = MFMA16(ahi, bfr, acc[nt]);
      acc[nt] = MFMA16(alo, bfr, acc[nt]);
    }
  }
#pragma unroll
  for (int nt = 0; nt < 4; nt++) {
    int n = wave * 64 + nt * 16 + col;
#pragma unroll
    for (int r = 0; r < 4; r++) {
      int t = t0 + quad * 4 + r;
      acc[nt][r] += (float)qc[(size_t)t * DMODEL + n];
    }
  }
  float sx[4], sq[4];
#pragma unroll
  for (int r = 0; r < 4; r++) {
    float s = 0, s2 = 0;
#pragma unroll
    for (int nt = 0; nt < 4; nt++) { float v = acc[nt][r]; s += v; s2 += v * v; }
    sx[r] = s; sq[r] = s2;
  }
#pragma unroll
  for (int off = 1; off < 16; off <<= 1) {
#pragma unroll
    for (int r = 0; r < 4; r++) {
      sx[r] += __shfl_xor(sx[r], off);
      sq[r] += __shfl_xor(sq[r], off);
    }
  }
  if (col == 0) {
#pragma unroll
    for (int r = 0; r < 4; r++) {
      lds_sx[wave][quad * 4 + r] = sx[r];
      lds_sq[wave][quad * 4 + r] = sq[r];
    }
  }
  __syncthreads();
#pragma unroll
  for (int r = 0; r < 4; r++) {
    int tl = quad * 4 + r;
    float tsx = lds_sx[0][tl] + lds_sx[1][tl] + lds_sx[2][tl] + lds_sx[3][tl];
    float tsq = lds_sq[0][tl] + lds_sq[1][tl] + lds_sq[2][tl] + lds_sq[3][tl];
    float mu = tsx * (1.0f / 256.0f);
    float var = tsq * (1.0f / 256.0f) - mu * mu;
    float rs = rsqrtf(var + 1e-6f);
    int t = t0 + tl;
#pragma unroll
    for (int nt = 0; nt < 4; nt++) {
      int n = wave * 64 + nt * 16 + col;
      float g = is32 ? ((const float*)gamma)[n] : (float)((const bf16_t*)gamma)[n];
      float bt = is32 ? ((const float*)beta)[n] : (float)((const bf16_t*)beta)[n];
      float val = (acc[nt][r] - mu) * rs * g + bt;
      if (is32) ((float*)out0)[(size_t)t * DMODEL + n] = val;
      else      ((bf16_t*)out0)[(size_t)t * DMODEL + n] = (bf16_t)val;
    }
  }
}

extern "C" void kernel_launch(void* const* d_in, const int* in_sizes, int n_in,
                              void* d_out, int out_size, void* d_ws, size_t ws_size,
                              hipStream_t stream) {
  (void)in_sizes; (void)n_in; (void)out_size;
  const void* qin   = d_in[0];
  const void* kin   = d_in[1];
  const void* vin   = d_in[2];
  const void* gp    = d_in[3];
  const int*  mask  = (const int*)d_in[4];
  const void* w_q   = d_in[5];
  const void* w_k   = d_in[6];
  const void* w_v   = d_in[7];
  const void* w_fc  = d_in[8];
  const void* gamma = d_in[9];
  const void* beta  = d_in[10];

  char* ws = (char*)d_ws;
  bf16_t* wt  = (bf16_t*)(ws);                  // 512 KB
  bf16_t* qc  = (bf16_t*)(ws + (1u << 20));     // 2 MB
  bf16_t* kc  = (bf16_t*)(ws + (3u << 20));     // 2 MB (reused as mbits later)
  bf16_t* vc  = (bf16_t*)(ws + (5u << 20));     // 2 MB
  bf16_t* qhi = (bf16_t*)(ws + (7u << 20));
  bf16_t* qlo = (bf16_t*)(ws + (9u << 20));
  bf16_t* khi = (bf16_t*)(ws + (11u << 20));
  bf16_t* klo = (bf16_t*)(ws + (13u << 20));
  bf16_t* vt  = (bf16_t*)(ws + (15u << 20));
  float* attn_out = (float*)(ws + (17u << 20)); // 4 MB
  int* flag = (int*)(ws + (21u << 20));
  unsigned int* mbits = (unsigned int*)(ws + (3u << 20));  // overlays kc (dead after k_proj)
  bf16_t* gpt = (bf16_t*)(ws + (22u << 20));    // 64 MB when available

  // bf16 gpt needs 22 MiB + 64 MiB of workspace; otherwise fall back to
  // duplicating the bias into the attno output region (no extra workspace).
  bool use_ws_gpt = ws_size >= (((size_t)86 << 20) + 64);

  const int NELEM_QKV = NTOK * DMODEL;

  hipLaunchKernelGGL(k_probe, dim3(1), dim3(64), 0, stream,
                     (const unsigned short*)qin, flag);
  hipLaunchKernelGGL(k_convert3, dim3((NELEM_QKV + 255) / 256, 3), dim3(256), 0, stream,
                     qin, kin, vin, qc, kc, vc, NELEM_QKV, flag);
  hipLaunchKernelGGL(k_transpose_w, dim3(8, 8, 4), dim3(32, 8), 0, stream,
                     w_q, w_k, w_v, w_fc, wt, flag);
  hipLaunchKernelGGL(k_proj, dim3(256, 1, 3), dim3(256), 0, stream,
                     qc, kc, vc, wt, qhi, qlo, khi, klo, vt);
  if (use_ws_gpt) {
    hipLaunchKernelGGL((k_tr_gp<0>), dim3(64, 64), dim3(256), 0, stream,
                       gp, gpt, d_out, mask, mbits, flag);
    hipLaunchKernelGGL((k_attn<0>), dim3(128, 8, 2), dim3(256), 0, stream,
                       qhi, qlo, khi, klo, vt, gpt, mbits, d_out, attn_out, flag);
  } else {
    hipLaunchKernelGGL((k_tr_gp<1>), dim3(64, 64), dim3(256), 0, stream,
                       gp, gpt, d_out, mask, mbits, flag);
    hipLaunchKernelGGL((k_attn<1>), dim3(128, 8, 2), dim3(256), 0, stream,
                       qhi, qlo, khi, klo, vt, gpt, mbits, d_out, attn_out, flag);
  }
  hipLaunchKernelGGL(k_fc_ln, dim3(256), dim3(256), 0, stream,
                     attn_out, wt + 3 * DMODEL * DMODEL, qc, gamma, beta, d_out, flag);
}

// Round 2
// 626.729 us; speedup vs baseline: 1.2754x; 1.2754x over previous
//
#include <hip/hip_runtime.h>
#include <hip/hip_bf16.h>

#define S_LEN 2048
#define BATCH 2
#define DMODEL 256
#define NHEAD 8
#define DKH 32
#define NTOK (S_LEN * BATCH)
#define OUT0_ELEMS ((size_t)NTOK * DMODEL)
#define SW (S_LEN / 32)  // mask words per row

typedef __bf16 bf16_t;
typedef __bf16 bf16x8 __attribute__((ext_vector_type(8)));
typedef __bf16 bf16x4 __attribute__((ext_vector_type(4)));
typedef float f32x4 __attribute__((ext_vector_type(4)));

#define MFMA16(a, b, c) __builtin_amdgcn_mfma_f32_16x16x32_bf16(a, b, c, 0, 0, 0)

// -------- kernel 0: dtype probe. flag=1 if inputs are fp32, 0 if bf16 -------
__global__ void k_probe(const unsigned short* __restrict__ q, int* __restrict__ flag) {
  if (threadIdx.x == 0 && blockIdx.x == 0) {
    int good = 0;
    for (int i = 0; i < 512; i += 2) {
      unsigned short u = q[i];
      int e = (u >> 7) & 0xFF;
      if ((u & 0x7FFF) == 0 || (e >= 110 && e <= 135)) good++;
    }
    *flag = (good >= 200) ? 0 : 1;
  }
}

// -------- kernel 0b: canonicalize q,k,v to bf16 (fused 3-tensor) ------------
__global__ __launch_bounds__(256) void k_convert3(
    const void* __restrict__ s0, const void* __restrict__ s1,
    const void* __restrict__ s2, bf16_t* __restrict__ d0,
    bf16_t* __restrict__ d1, bf16_t* __restrict__ d2, int n,
    const int* __restrict__ flag) {
  const void* src = (blockIdx.y == 0) ? s0 : (blockIdx.y == 1) ? s1 : s2;
  bf16_t* dst = (blockIdx.y == 0) ? d0 : (blockIdx.y == 1) ? d1 : d2;
  int i = blockIdx.x * 256 + threadIdx.x;
  if (i >= n) return;
  if (*flag) dst[i] = (bf16_t)((const float*)src)[i];
  else       dst[i] = ((const bf16_t*)src)[i];
}

// ---------------- kernel 1: transpose the 4 weight matrices -----------------
__global__ __launch_bounds__(256) void k_transpose_w(
    const void* __restrict__ w_q, const void* __restrict__ w_k,
    const void* __restrict__ w_v, const void* __restrict__ w_fc,
    bf16_t* __restrict__ wt, const int* __restrict__ flag) {
  __shared__ bf16_t tile[32][33];
  const void* w = (blockIdx.z == 0) ? w_q : (blockIdx.z == 1) ? w_k
                                       : (blockIdx.z == 2) ? w_v : w_fc;
  int f = *flag;
  bf16_t* o = wt + (size_t)blockIdx.z * DMODEL * DMODEL;
  int tx = threadIdx.x, ty = threadIdx.y;
  int x = blockIdx.x * 32 + tx;
  int y0 = blockIdx.y * 32;
  for (int j = ty; j < 32; j += 8) {
    size_t idx = (size_t)(y0 + j) * DMODEL + x;
    float v = f ? ((const float*)w)[idx] : (float)((const bf16_t*)w)[idx];
    tile[j][tx] = (bf16_t)v;
  }
  __syncthreads();
  for (int j = ty; j < 32; j += 8)
    o[(size_t)(blockIdx.x * 32 + j) * DMODEL + y0 + tx] = tile[tx][j];
}

// ---------------- kernel 2: QKV projections via MFMA ------------------------
__global__ __launch_bounds__(256) void k_proj(
    const bf16_t* __restrict__ qin, const bf16_t* __restrict__ kin,
    const bf16_t* __restrict__ vin, const bf16_t* __restrict__ wt,
    bf16_t* __restrict__ qhi, bf16_t* __restrict__ qlo,
    bf16_t* __restrict__ khi, bf16_t* __restrict__ klo,
    bf16_t* __restrict__ vt) {
  int mat = blockIdx.z;
  const bf16_t* x = (mat == 0) ? qin : (mat == 1) ? kin : vin;
  const bf16_t* wm = wt + (size_t)mat * DMODEL * DMODEL;
  int t0 = blockIdx.x * 16;
  int lane = threadIdx.x & 63, wave = threadIdx.x >> 6;
  int col = lane & 15, quad = lane >> 4;
  f32x4 acc[4] = {};
  const bf16_t* xrow = x + (size_t)(t0 + col) * DMODEL + quad * 8;
  for (int kk = 0; kk < 8; kk++) {
    bf16x8 a = *(const bf16x8*)(xrow + kk * 32);
#pragma unroll
    for (int nt = 0; nt < 4; nt++) {
      int n0 = wave * 64 + nt * 16;
      bf16x8 bw = *(const bf16x8*)(wm + (size_t)(n0 + col) * DMODEL + kk * 32 + quad * 8);
      acc[nt] = MFMA16(a, bw, acc[nt]);
    }
  }
  const float qscale = 0.17677669529663687f;  // 1/sqrt(32)
#pragma unroll
  for (int nt = 0; nt < 4; nt++) {
    int n = wave * 64 + nt * 16 + col;
    int h = n >> 5, dk = n & 31;
#pragma unroll
    for (int r = 0; r < 4; r++) {
      int t = t0 + quad * 4 + r;
      int s = t >> 1, bb = t & 1;
      float val = acc[nt][r];
      if (mat == 0) val *= qscale;
      if (mat <= 1) {
        bf16_t hi = (bf16_t)val;
        bf16_t lo = (bf16_t)(val - (float)hi);
        size_t idx = ((size_t)(bb * NHEAD + h) * S_LEN + s) * DKH + dk;
        if (mat == 0) { qhi[idx] = hi; qlo[idx] = lo; }
        else         { khi[idx] = hi; klo[idx] = lo; }
      } else {
        vt[((size_t)(bb * NHEAD + h) * DKH + dk) * S_LEN + s] = (bf16_t)val;
      }
    }
  }
}

// ---------------- kernel 2b: transpose graph_pos + pack mask ----------------
// gp [k=2048][q=2048][h=8] -> bias in [h][q][k] layout.
// MODE 0: single bf16 copy into gpt (workspace).
// MODE 1: flag-dtype copies duplicated into the attno region of d_out for
//         b=0 and b=1 (read-then-overwritten in place by k_attn).
// Also bit-packs mask: 64 uint32 words per block.
template <int MODE>
__global__ __launch_bounds__(256) void k_tr_gp(
    const void* __restrict__ gp, bf16_t* __restrict__ gpt,
    void* __restrict__ attno_raw, const int* __restrict__ mask,
    unsigned int* __restrict__ mbits, const int* __restrict__ flag) {
  __shared__ float tile[32][8][32];  // [k][h][q], 32 KB
  int is32 = *flag;
  int tid = threadIdx.x;
  int k0 = blockIdx.x * 32, q0 = blockIdx.y * 32;
  int ci = tid & 63, krl = tid >> 6;
#pragma unroll
  for (int p = 0; p < 8; p++) {
    int kr = p * 4 + krl;
    size_t base = ((size_t)(k0 + kr) * S_LEN + q0) * NHEAD + ci * 4;
    f32x4 v;
    if (is32) {
      v = __builtin_nontemporal_load((const f32x4*)((const float*)gp + base));
    } else {
      bf16x4 bv = *(const bf16x4*)((const bf16_t*)gp + base);
      v[0] = (float)bv[0]; v[1] = (float)bv[1];
      v[2] = (float)bv[2]; v[3] = (float)bv[3];
    }
    int qq = ci >> 1, hb = (ci & 1) * 4;  // 4 consecutive elems = 4 h of one q
    tile[kr][hb + 0][qq] = v[0];
    tile[kr][hb + 1][qq] = v[1];
    tile[kr][hb + 2][qq] = v[2];
    tile[kr][hb + 3][qq] = v[3];
  }
  __syncthreads();
  int h = tid >> 5, q = tid & 31;
  if (MODE == 0) {
    bf16_t* orow = gpt + ((size_t)h * S_LEN + q0 + q) * S_LEN + k0;
#pragma unroll
    for (int j = 0; j < 4; j++) {
      bf16x8 o;
#pragma unroll
      for (int i2 = 0; i2 < 8; i2++) o[i2] = (bf16_t)tile[j * 8 + i2][h][q];
      *(bf16x8*)(orow + j * 8) = o;
    }
  } else {
    size_t ro = ((size_t)h * S_LEN + q0 + q) * S_LEN + k0;
    size_t bs = (size_t)NHEAD * S_LEN * S_LEN;
    if (is32) {
      float* o0 = (float*)attno_raw + OUT0_ELEMS + ro;
#pragma unroll
      for (int j = 0; j < 8; j++) {
        f32x4 o;
#pragma unroll
        for (int i2 = 0; i2 < 4; i2++) o[i2] = tile[j * 4 + i2][h][q];
        *(f32x4*)(o0 + j * 4) = o;
        *(f32x4*)(o0 + bs + j * 4) = o;
      }
    } else {
      bf16_t* o0 = (bf16_t*)attno_raw + OUT0_ELEMS + ro;
#pragma unroll
      for (int j = 0; j < 4; j++) {
        bf16x8 o;
#pragma unroll
        for (int i2 = 0; i2 < 8; i2++) o[i2] = (bf16_t)tile[j * 8 + i2][h][q];
        *(bf16x8*)(o0 + j * 8) = o;
        *(bf16x8*)(o0 + bs + j * 8) = o;
      }
    }
  }
  // ---- mask bit-pack: this block handles 64 words (64*32 mask ints) ----
  if (tid < 64) {
    int w = (blockIdx.y * 64 + blockIdx.x) * 64 + tid;  // 0..262143
    const int* src = mask + (size_t)w * 32;
    unsigned int bits = 0;
#pragma unroll
    for (int j = 0; j < 32; j += 4) {
      int4 m = *(const int4*)(src + j);
      if (m.x) bits |= 1u << j;
      if (m.y) bits |= 1u << (j + 1);
      if (m.z) bits |= 1u << (j + 2);
      if (m.w) bits |= 1u << (j + 3);
    }
    mbits[w] = bits;
  }
}

// ---------------- kernel 3: attention ---------------------------------------
// Flat grid of 2048 blocks with XCD-aware swizzle: XCD x (= L&7) owns
// head-pairs p = x and p = x+8, so each XCD's L2 only holds ~2 heads of
// K/V/Q (~0.9 MB << 4 MiB) -> K loads are L2 hits.
// BMODE 0: bias read as bf16 from gpt[h][q][k] (workspace).
// BMODE 1: bias read (flag dtype) from the attno region of d_out itself,
//          then overwritten with attno by the same wave (data-dep ordered).
template <int BMODE>
__global__ __launch_bounds__(256) void k_attn(
    const bf16_t* __restrict__ qhi, const bf16_t* __restrict__ qlo,
    const bf16_t* __restrict__ khi, const bf16_t* __restrict__ klo,
    const bf16_t* __restrict__ vtg, const bf16_t* __restrict__ gpt,
    const unsigned int* __restrict__ mbits, void* __restrict__ attno_raw,
    float* __restrict__ attn_out, const int* __restrict__ flag) {
  __shared__ __align__(16) bf16_t lds_p[4][16][72];   // also reused for O-combine
  __shared__ __align__(16) bf16_t lds_pb[4][16][72];
  __shared__ float lds_m[4][16];
  __shared__ float lds_l[4][16];

  int is32 = *flag;
  float*  attno_f = (float*)attno_raw + OUT0_ELEMS;
  bf16_t* attno_b = (bf16_t*)attno_raw + OUT0_ELEMS;

  // ---- XCD-aware block swizzle ----
  int L = blockIdx.x;
  int j = L >> 3;
  int p = (L & 7) + ((j >> 7) << 3);  // head-pair index 0..15
  int h = p >> 1, b = p & 1;
  int q0 = (j & 127) * 16;

  int lane = threadIdx.x & 63, wave = threadIdx.x >> 6;
  int col = lane & 15, quad = lane >> 4;
  int kbase = wave * 512;
  size_t head = (size_t)(b * NHEAD + h);
  const bf16_t* Qh = qhi + head * S_LEN * DKH;
  const bf16_t* Ql = qlo + head * S_LEN * DKH;
  const bf16_t* Kh = khi + head * S_LEN * DKH;
  const bf16_t* Kl = klo + head * S_LEN * DKH;
  const bf16_t* Vt = vtg + head * DKH * S_LEN;
  const unsigned int* mrow =
      mbits + ((size_t)b * S_LEN + q0 + col) * SW + (kbase >> 5);
  const bf16_t* gprow = gpt + ((size_t)h * S_LEN + q0 + col) * S_LEN + kbase;
  size_t brow = head * S_LEN * S_LEN + (size_t)(q0 + col) * S_LEN + kbase;

  bf16x8 qhF = *(const bf16x8*)(Qh + (q0 + col) * DKH + quad * 8);
  bf16x8 qlF = *(const bf16x8*)(Ql + (q0 + col) * DKH + quad * 8);

  // ---- pass 1: per-wave online softmax stats over this wave's 512 keys ----
  // fully unrolled so the compiler can hoist K loads off the m/l chain
  float m = -3.0e38f, l = 0.f;
#pragma unroll
  for (int t = 0; t < 32; t++) {
    int k0 = kbase + t * 16;
    bf16x8 khF = *(const bf16x8*)(Kh + (size_t)(k0 + col) * DKH + quad * 8);
    bf16x8 klF = *(const bf16x8*)(Kl + (size_t)(k0 + col) * DKH + quad * 8);
    f32x4 sc = {};
    sc = MFMA16(khF, qhF, sc);
    sc = MFMA16(khF, qlF, sc);
    sc = MFMA16(klF, qhF, sc);
    unsigned int mw = mrow[t >> 1];
    int mb = (int)(mw >> ((t & 1) * 16 + quad * 4)) & 0xF;
    float s0 = (mb & 1) ? sc[0] : -1e9f;
    float s1 = (mb & 2) ? sc[1] : -1e9f;
    float s2 = (mb & 4) ? sc[2] : -1e9f;
    float s3 = (mb & 8) ? sc[3] : -1e9f;
    float tm = fmaxf(fmaxf(s0, s1), fmaxf(s2, s3));
    float m2 = fmaxf(m, tm);
    l = l * __expf(m - m2) + __expf(s0 - m2) + __expf(s1 - m2) +
        __expf(s2 - m2) + __expf(s3 - m2);
    m = m2;
  }
#pragma unroll
  for (int off = 16; off < 64; off <<= 1) {
    float mo = __shfl_xor(m, off);
    float lo2 = __shfl_xor(l, off);
    float mn = fmaxf(m, mo);
    l = l * __expf(m - mn) + lo2 * __expf(mo - mn);
    m = mn;
  }
  if (lane < 16) { lds_m[wave][lane] = m; lds_l[wave][lane] = l; }
  __syncthreads();
  {
    float mg = -3.0e38f;
#pragma unroll
    for (int w = 0; w < 4; w++) mg = fmaxf(mg, lds_m[w][col]);
    float lg = 0.f;
#pragma unroll
    for (int w = 0; w < 4; w++) lg += lds_l[w][col] * __expf(lds_m[w][col] - mg);
    m = mg;
    l = lg;
  }
  float invl = 1.0f / l;

  // ---- pass 2: recompute, emit attno, accumulate PV ----
  // no __syncthreads in this loop: lds_p/lds_pb are per-wave private.
  f32x4 oacc[2] = {};
  for (int c = 0; c < 8; c++) {
#pragma unroll
    for (int tt = 0; tt < 4; tt++) {
      int k0 = kbase + c * 64 + tt * 16;
      bf16x8 khF = *(const bf16x8*)(Kh + (size_t)(k0 + col) * DKH + quad * 8);
      bf16x8 klF = *(const bf16x8*)(Kl + (size_t)(k0 + col) * DKH + quad * 8);
      f32x4 sc = {};
      sc = MFMA16(khF, qhF, sc);
      sc = MFMA16(khF, qlF, sc);
      sc = MFMA16(klF, qhF, sc);
      unsigned int mw = mrow[c * 2 + (tt >> 1)];
      int mb = (int)(mw >> ((tt & 1) * 16 + quad * 4)) & 0xF;
      float bias[4];
      if (BMODE == 0) {
        bf16x4 b4 = *(const bf16x4*)(gprow + c * 64 + tt * 16 + quad * 4);
#pragma unroll
        for (int r = 0; r < 4; r++) bias[r] = (float)b4[r];
      } else {
        if (is32) {
          f32x4 b4 = *(const f32x4*)(attno_f + brow + c * 64 + tt * 16 + quad * 4);
#pragma unroll
          for (int r = 0; r < 4; r++) bias[r] = b4[r];
        } else {
          bf16x4 b4 = *(const bf16x4*)(attno_b + brow + c * 64 + tt * 16 + quad * 4);
#pragma unroll
          for (int r = 0; r < 4; r++) bias[r] = (float)b4[r];
        }
      }
      bf16x4 pv, pbv;
#pragma unroll
      for (int r = 0; r < 4; r++) {
        float sv = (mb & (1 << r)) ? sc[r] : -1e9f;
        float p = __expf(sv - m) * invl;
        pv[r] = (bf16_t)p;
        pbv[r] = (bf16_t)(p * bias[r]);
      }
      *(bf16x4*)&lds_p[wave][col][tt * 16 + quad * 4] = pv;
      *(bf16x4*)&lds_pb[wave][col][tt * 16 + quad * 4] = pbv;
    }
    {  // attno write: 16 rows x 64 keys per wave-chunk (plain stores: they
       // coalesce through L2 into full lines; NT stores amplified 2.6x)
      int r = lane >> 2, part = lane & 3;
      size_t base = head * S_LEN * S_LEN + (size_t)(q0 + r) * S_LEN + kbase + c * 64 + part * 16;
      if (is32) {
#pragma unroll
        for (int jj = 0; jj < 4; jj++) {
          f32x4 vv;
#pragma unroll
          for (int ii = 0; ii < 4; ii++)
            vv[ii] = (float)lds_p[wave][r][part * 16 + jj * 4 + ii];
          *(f32x4*)(attno_f + base + jj * 4) = vv;
        }
      } else {
        bf16x8 v0 = *(const bf16x8*)&lds_p[wave][r][part * 16];
        bf16x8 v1 = *(const bf16x8*)&lds_p[wave][r][part * 16 + 8];
        *(bf16x8*)(attno_b + base) = v0;
        *(bf16x8*)(attno_b + base + 8) = v1;
      }
    }
#pragma unroll
    for (int ks = 0; ks < 2; ks++) {
      bf16x8 pf = *(const bf16x8*)&lds_pb[wave][col][ks * 32 + quad * 8];
#pragma unroll
      for (int dt = 0; dt < 2; dt++) {
        bf16x8 vf = *(const bf16x8*)(Vt + (size_t)(dt * 16 + col) * S_LEN + kbase + c * 64 + ks * 32 + quad * 8);
        oacc[dt] = MFMA16(vf, pf, oacc[dt]);
      }
    }
  }
  // combine O across waves; reuse lds_p (per-wave regions, 16x34 fp32 fits
  // inside 16x72 bf16) so total LDS stays at ~19 KB -> 8 blocks/CU.
  {
    float* lo = (float*)&lds_p[wave][0][0];
#pragma unroll
    for (int dt = 0; dt < 2; dt++)
#pragma unroll
      for (int r = 0; r < 4; r++)
        lo[col * 34 + dt * 16 + quad * 4 + r] = oacc[dt][r];
  }
  __syncthreads();
  if (wave == 0) {
    int t = (q0 + col) * BATCH + b;
#pragma unroll
    for (int dt = 0; dt < 2; dt++) {
      f32x4 vv = {};
#pragma unroll
      for (int w = 0; w < 4; w++) {
        const float* lw = (const float*)&lds_p[w][0][0];
#pragma unroll
        for (int r2 = 0; r2 < 4; r2++)
          vv[r2] += lw[col * 34 + dt * 16 + quad * 4 + r2];
      }
      *(f32x4*)(attn_out + (size_t)t * DMODEL + h * DKH + dt * 16 + quad * 4) = vv;
    }
  }
}

// ---------------- kernel 4: FC + residual + LayerNorm -----------------------
__global__ __launch_bounds__(256) void k_fc_ln(
    const float* __restrict__ attn_out, const bf16_t* __restrict__ wtfc,
    const bf16_t* __restrict__ qc, const void* __restrict__ gamma,
    const void* __restrict__ beta, void* __restrict__ out0,
    const int* __restrict__ flag) {
  __shared__ float lds_sx[4][16];
  __shared__ float lds_sq[4][16];
  int is32 = *flag;
  int t0 = blockIdx.x * 16;
  int lane = threadIdx.x & 63, wave = threadIdx.x >> 6;
  int col = lane & 15, quad = lane >> 4;
  f32x4 acc[4] = {};
  const float* arow = attn_out + (size_t)(t0 + col) * DMODEL + quad * 8;
  for (int kk = 0; kk < 8; kk++) {
    float4 a0 = *(const float4*)(arow + kk * 32);
    float4 a1 = *(const float4*)(arow + kk * 32 + 4);
    float av[8] = {a0.x, a0.y, a0.z, a0.w, a1.x, a1.y, a1.z, a1.w};
    bf16x8 ahi, alo;
#pragma unroll
    for (int j = 0; j < 8; j++) {
      bf16_t hi = (bf16_t)av[j];
      ahi[j] = hi;
      alo[j] = (bf16_t)(av[j] - (float)hi);
    }
#pragma unroll
    for (int nt = 0; nt < 4; nt++) {
      int n0 = wave * 64 + nt * 16;
      bf16x8 bfr = *(const bf16x8*)(wtfc + (size_t)(n0 + col) * DMODEL + kk * 32 + quad * 8);
      acc[nt] = MFMA16(ahi, bfr, acc[nt]);
      acc[nt] = MFMA16(alo, bfr, acc[nt]);
    }
  }
#pragma unroll
  for (int nt = 0; nt < 4; nt++) {
    int n = wave * 64 + nt * 16 + col;
#pragma unroll
    for (int r = 0; r < 4; r++) {
      int t = t0 + quad * 4 + r;
      acc[nt][r] += (float)qc[(size_t)t * DMODEL + n];
    }
  }
  float sx[4], sq[4];
#pragma unroll
  for (int r = 0; r < 4; r++) {
    float s = 0, s2 = 0;
#pragma unroll
    for (int nt = 0; nt < 4; nt++) { float v = acc[nt][r]; s += v; s2 += v * v; }
    sx[r] = s; sq[r] = s2;
  }
#pragma unroll
  for (int off = 1; off < 16; off <<= 1) {
#pragma unroll
    for (int r = 0; r < 4; r++) {
      sx[r] += __shfl_xor(sx[r], off);
      sq[r] += __shfl_xor(sq[r], off);
    }
  }
  if (col == 0) {
#pragma unroll
    for (int r = 0; r < 4; r++) {
      lds_sx[wave][quad * 4 + r] = sx[r];
      lds_sq[wave][quad * 4 + r] = sq[r];
    }
  }
  __syncthreads();
#pragma unroll
  for (int r = 0; r < 4; r++) {
    int tl = quad * 4 + r;
    float tsx = lds_sx[0][tl] + lds_sx[1][tl] + lds_sx[2][tl] + lds_sx[3][tl];
    float tsq = lds_sq[0][tl] + lds_sq[1][tl] + lds_sq[2][tl] + lds_sq[3][tl];
    float mu = tsx * (1.0f / 256.0f);
    float var = tsq * (1.0f / 256.0f) - mu * mu;
    float rs = rsqrtf(var + 1e-6f);
    int t = t0 + tl;
#pragma unroll
    for (int nt = 0; nt < 4; nt++) {
      int n = wave * 64 + nt * 16 + col;
      float g = is32 ? ((const float*)gamma)[n] : (float)((const bf16_t*)gamma)[n];
      float bt = is32 ? ((const float*)beta)[n] : (float)((const bf16_t*)beta)[n];
      float val = (acc[nt][r] - mu) * rs * g + bt;
      if (is32) ((float*)out0)[(size_t)t * DMODEL + n] = val;
      else      ((bf16_t*)out0)[(size_t)t * DMODEL + n] = (bf16_t)val;
    }
  }
}

extern "C" void kernel_launch(void* const* d_in, const int* in_sizes, int n_in,
                              void* d_out, int out_size, void* d_ws, size_t ws_size,
                              hipStream_t stream) {
  (void)in_sizes; (void)n_in; (void)out_size;
  const void* qin   = d_in[0];
  const void* kin   = d_in[1];
  const void* vin   = d_in[2];
  const void* gp    = d_in[3];
  const int*  mask  = (const int*)d_in[4];
  const void* w_q   = d_in[5];
  const void* w_k   = d_in[6];
  const void* w_v   = d_in[7];
  const void* w_fc  = d_in[8];
  const void* gamma = d_in[9];
  const void* beta  = d_in[10];

  char* ws = (char*)d_ws;
  bf16_t* wt  = (bf16_t*)(ws);                  // 512 KB
  bf16_t* qc  = (bf16_t*)(ws + (1u << 20));     // 2 MB
  bf16_t* kc  = (bf16_t*)(ws + (3u << 20));     // 2 MB (reused as mbits later)
  bf16_t* vc  = (bf16_t*)(ws + (5u << 20));     // 2 MB
  bf16_t* qhi = (bf16_t*)(ws + (7u << 20));
  bf16_t* qlo = (bf16_t*)(ws + (9u << 20));
  bf16_t* khi = (bf16_t*)(ws + (11u << 20));
  bf16_t* klo = (bf16_t*)(ws + (13u << 20));
  bf16_t* vt  = (bf16_t*)(ws + (15u << 20));
  float* attn_out = (float*)(ws + (17u << 20)); // 4 MB
  int* flag = (int*)(ws + (21u << 20));
  unsigned int* mbits = (unsigned int*)(ws + (3u << 20));  // overlays kc (dead after k_proj)
  bf16_t* gpt = (bf16_t*)(ws + (22u << 20));    // 64 MB when available

  // bf16 gpt needs 22 MiB + 64 MiB of workspace; otherwise fall back to
  // duplicating the bias into the attno output region (no extra workspace).
  bool use_ws_gpt = ws_size >= (((size_t)86 << 20) + 64);

  const int NELEM_QKV = NTOK * DMODEL;

  hipLaunchKernelGGL(k_probe, dim3(1), dim3(64), 0, stream,
                     (const unsigned short*)qin, flag);
  hipLaunchKernelGGL(k_convert3, dim3((NELEM_QKV + 255) / 256, 3), dim3(256), 0, stream,
                     qin, kin, vin, qc, kc, vc, NELEM_QKV, flag);
  hipLaunchKernelGGL(k_transpose_w, dim3(8, 8, 4), dim3(32, 8), 0, stream,
                     w_q, w_k, w_v, w_fc, wt, flag);
  hipLaunchKernelGGL(k_proj, dim3(256, 1, 3), dim3(256), 0, stream,
                     qc, kc, vc, wt, qhi, qlo, khi, klo, vt);
  if (use_ws_gpt) {
    hipLaunchKernelGGL((k_tr_gp<0>), dim3(64, 64), dim3(256), 0, stream,
                       gp, gpt, d_out, mask, mbits, flag);
    hipLaunchKernelGGL((k_attn<0>), dim3(2048), dim3(256), 0, stream,
                       qhi, qlo, khi, klo, vt, gpt, mbits, d_out, attn_out, flag);
  } else {
    hipLaunchKernelGGL((k_tr_gp<1>), dim3(64, 64), dim3(256), 0, stream,
                       gp, gpt, d_out, mask, mbits, flag);
    hipLaunchKernelGGL((k_attn<1>), dim3(2048), dim3(256), 0, stream,
                       qhi, qlo, khi, klo, vt, gpt, mbits, d_out, attn_out, flag);
  }
  hipLaunchKernelGGL(k_fc_ln, dim3(256), dim3(256), 0, stream,
                     attn_out, wt + 3 * DMODEL * DMODEL, qc, gamma, beta, d_out, flag);
}